// Round 9
// baseline (69152.649 us; speedup 1.0000x reference)
//
#include <hip/hip_runtime.h>

typedef __attribute__((ext_vector_type(4))) float f4;
typedef __attribute__((ext_vector_type(8))) short frag8;
typedef unsigned long long u64;
typedef unsigned int u32;
typedef unsigned short u16;

#define ALPHA 0.3f

// ---- ws layout (bytes) ----
#define WHH_OFF   0ull                 // 3072*1024 bf16 = 6291456
#define WIH_OFF   6291456ull           // 3072*128 bf16  = 786432
#define HBUF_OFF  7077888ull           // 2 parities * 8 groups * 65536 = 1048576
#define FLG_OFF   8126464ull           // 8 groups * 32 u32 monotonic step flags
#define ST1_OFF   8159232ull           // 256*2 fp32 = 2048
#define XCC_OFF   8161280ull           // 256 u32 per-WG xcc-id (+1)
#define ZERO_LEN  1084416ull           // hbuf + flags + st1 + xcc

__device__ __forceinline__ u16 f2bf(float f) {
  u32 u = __float_as_uint(f);
  u32 r = (u + 0x7FFFu + ((u >> 16) & 1u)) >> 16;
  return (u16)r;
}
__device__ __forceinline__ float bf2f(u16 h) {
  return __uint_as_float(((u32)h) << 16);
}
__device__ __forceinline__ float sigmf(float x) {
  float e = __expf(-fabsf(x));
  float s = 1.0f / (1.0f + e);
  return x >= 0.f ? s : 1.0f - s;
}
__device__ __forceinline__ float tanhf_(float x) {
  float e = __expf(-2.0f * fabsf(x));
  float t = (1.0f - e) / (1.0f + e);
  return x >= 0.f ? t : -t;
}
__device__ __forceinline__ frag8 pack_bf16(f4 a, f4 b) {
  union { u16 h[8]; frag8 f; } u;
  u.h[0] = f2bf(a[0]); u.h[1] = f2bf(a[1]); u.h[2] = f2bf(a[2]); u.h[3] = f2bf(a[3]);
  u.h[4] = f2bf(b[0]); u.h[5] = f2bf(b[1]); u.h[6] = f2bf(b[2]); u.h[7] = f2bf(b[3]);
  return u.f;
}

// fp32 -> bf16 weight conversion (W_hh then W_ih), exact-sized grid.
__global__ void prep_bf16(const float* __restrict__ whh_f32,
                          const float* __restrict__ wih_f32,
                          u16* __restrict__ whh, u16* __restrict__ wih) {
  int i = blockIdx.x * 256 + threadIdx.x;
  const int nhh = 3072 * 1024;
  if (i < nhh) whh[i] = f2bf(whh_f32[i]);
  else         wih[i - nhh] = f2bf(wih_f32[i - nhh]);
}

#define ACC_ZERO() do {                                                        \
  _Pragma("unroll") for (int bh_ = 0; bh_ < 2; ++bh_) {                        \
    _Pragma("unroll") for (int rt_ = 0; rt_ < 6; ++rt_) acc[bh_][rt_] = zz;    \
    accn[bh_][0] = zz; accn[bh_][1] = zz; }                                    \
} while (0)

#define IH_MFMA() do {                                                         \
  _Pragma("unroll") for (int rt_ = 0; rt_ < 4; ++rt_) {                        \
    acc[0][rt_] = __builtin_amdgcn_mfma_f32_16x16x32_bf16(smf0, wihf[rt_], acc[0][rt_], 0, 0, 0); \
    acc[1][rt_] = __builtin_amdgcn_mfma_f32_16x16x32_bf16(smf1, wihf[rt_], acc[1][rt_], 0, 0, 0); } \
  _Pragma("unroll") for (int nt_ = 0; nt_ < 2; ++nt_) {                        \
    accn[0][nt_] = __builtin_amdgcn_mfma_f32_16x16x32_bf16(smf0, wihf[4 + nt_], accn[0][nt_], 0, 0, 0); \
    accn[1][nt_] = __builtin_amdgcn_mfma_f32_16x16x32_bf16(smf1, wihf[4 + nt_], accn[1][nt_], 0, 0, 0); } \
} while (0)

// 24 hh MFMAs consuming af[2j], af[2j+1].
#define HH_CHUNK(j) do {                                                       \
  _Pragma("unroll") for (int kk_ = 0; kk_ < 2; ++kk_) {                        \
    const int kb_ = 2 * (j) + kk_;                                             \
    _Pragma("unroll") for (int rt_ = 0; rt_ < 6; ++rt_) {                      \
      acc[0][rt_] = __builtin_amdgcn_mfma_f32_16x16x32_bf16(af[kb_][0], whhf[kb_][rt_], acc[0][rt_], 0, 0, 0); \
      acc[1][rt_] = __builtin_amdgcn_mfma_f32_16x16x32_bf16(af[kb_][1], whhf[kb_][rt_], acc[1][rt_], 0, 0, 0); } } \
} while (0)

// 4 dwordx4 coherent loads; issue order = vmcnt order. SC = cache bits:
// "sc0" (XCD-local, L2 coherence point) or "sc0 sc1" (device, LLC).
#define AF_LOAD(j, SC) asm volatile(                                           \
  "global_load_dwordx4 %0, %4, off " SC "\n\t"                                 \
  "global_load_dwordx4 %1, %4, off offset:1024 " SC "\n\t"                     \
  "global_load_dwordx4 %2, %4, off offset:2048 " SC "\n\t"                     \
  "global_load_dwordx4 %3, %4, off offset:3072 " SC                            \
  : "=&v"(af[2 * (j)][0]), "=&v"(af[2 * (j)][1]),                              \
    "=&v"(af[2 * (j) + 1][0]), "=&v"(af[2 * (j) + 1][1])                       \
  : "v"(pb + (j) * 4096))

#define H_STORE(SC) asm volatile("global_store_dwordx2 %0, %1, off " SC        \
  :: "v"(hwrite + off), "v"(pk) : "memory")
#define POLL_LOAD(SC) asm volatile("global_load_dword %0, %1, off " SC "\n\t"  \
  "s_waitcnt vmcnt(0)" : "=v"(fv) : "v"(fp) : "memory")

// Persistent GRU recurrence. 256 WGs = 8 groups (batch slices of 32) x 32 WGs
// (32 H-cols each). Group g = wg&7: under round-robin dispatch the 32 WGs of a
// group share one XCD -> h exchange (af loads, h stores) runs sc0-only through
// that XCD's L2 (proven R8: FETCH_SIZE 2.63e6 -> 9.4e4 KB, passed).
// This round: step-barrier flags localized too, hang-proof:
//   arrive = double store (sc0 then sc0 sc1); wait = sc0 poll with bounded
//   escalation to sc0 sc1 (sees the LLC copy -> provably terminates).
// Co-location verified at runtime (barrier-style check, no leader); fallback
// verdict -> all device-scope ops == proven R1 behavior.
__global__ __launch_bounds__(256, 1) void gru_kernel(
    const float* __restrict__ x,       // [256][1024][128]
    const float* __restrict__ b_ih,    // [3072]
    const float* __restrict__ b_hh,    // [3072]
    const u16* __restrict__ whh,       // [3072][1024] bf16
    const u16* __restrict__ wih,       // [3072][128] bf16
    u64* __restrict__ hbuf,            // [2][8][8192] u64 (64KB per (p,g))
    u32* __restrict__ flags,           // [8][32] monotonic step counters
    u32* __restrict__ xccarr,          // [256] xcc-id + 1
    float* __restrict__ st1)           // [256][2]
{
  __shared__ f4 xbuf[4096];            // 64 KB: [4 waves][128 gr][8 b-quads] swizzled
  const int wg = blockIdx.x;
  const int g = wg & 7, w = wg >> 3;   // group spans one XCD under round-robin
  const int tid = threadIdx.x;
  const int v = tid >> 6;              // wave = K-slice of 256
  const int l = tid & 63;
  const int lm = l & 15, lq = l >> 4;

  // ---- load weight fragments into registers (persistent) ----
  frag8 whhf[8][6];
  frag8 wihf[6];
#pragma unroll
  for (int rt = 0; rt < 6; ++rt) {
    int grow = (rt >> 1) * 1024 + w * 32 + (rt & 1) * 16 + lm;  // global gate row
    wihf[rt] = *(const frag8*)(wih + grow * 128 + v * 32 + lq * 8);
#pragma unroll
    for (int kb = 0; kb < 8; ++kb)
      whhf[kb][rt] = *(const frag8*)(whh + grow * 1024 + v * 256 + kb * 32 + lq * 8);
  }

  // ---- update-phase constants ----
  const int uc = tid & 31;
  const int ub0 = (tid >> 5) << 2;
  const int colg = w * 32 + uc;
  const float bir = b_ih[colg],         bhr = b_hh[colg];
  const float biz = b_ih[1024 + colg],  bhz = b_hh[1024 + colg];
  const float bin_ = b_ih[2048 + colg], bhn = b_hh[2048 + colg];
  f4 hprev = {0.f, 0.f, 0.f, 0.f};

  const float* xb0 = x + (size_t)(g * 32 + lm) * 131072 + v * 32 + lq * 8;
  const float* xb1 = x + (size_t)(g * 32 + 16 + lm) * 131072 + v * 32 + lq * 8;

  u32* flagbase = flags + (g << 5);
  u32* fself = flagbase + w;
  const f4 zz = {0.f, 0.f, 0.f, 0.f};
  const float A1 = 1.0f - ALPHA;

  // ---- one-time XCD co-location check: barrier-style, no leader ----
  u32 myxcc;
  asm volatile("s_getreg_b32 %0, hwreg(HW_REG_XCC_ID)" : "=s"(myxcc));
  myxcc &= 15u;
  if (tid == 0) {
    u32 pub = myxcc + 1u;
    asm volatile("global_store_dword %0, %1, off sc0 sc1"
                 :: "v"(xccarr + wg), "v"(pub) : "memory");
  }
  if (tid < 64) {
    const u32* xp = xccarr + ((((tid & 31) << 3) | g));  // member (tid&31) of group g
    u32 vv;
    while (1) {
      asm volatile("global_load_dword %0, %1, off sc0 sc1\n\ts_waitcnt vmcnt(0)"
                   : "=v"(vv) : "v"(xp) : "memory");
      if (__ballot(vv != 0u) == ~0ull) break;
      __builtin_amdgcn_s_sleep(1);
    }
    u32 same = (__ballot(vv == myxcc + 1u) == ~0ull) ? 1u : 0u;
    if (tid == 0) *(volatile u32*)&xbuf[0] = same;
  }
  __syncthreads();
  const bool locl = (*(volatile u32*)&xbuf[0]) != 0u;
  __syncthreads();   // xbuf[0] consumed before first loop LDS write

  // ---- prologue: EMA(0) = x(0); pack; gi(0) MFMAs ----
  f4 e0a = *(const f4*)xb0, e0b = *(const f4*)(xb0 + 4);
  f4 e1a = *(const f4*)xb1, e1b = *(const f4*)(xb1 + 4);
  frag8 smf0 = pack_bf16(e0a, e0b), smf1 = pack_bf16(e1a, e1b);
  f4 acc[2][6], accn[2][2];
  ACC_ZERO();
  IH_MFMA();

#pragma unroll 1
  for (int t = 0; t < 1024; ++t) {
    const char* hrd = (const char*)hbuf + ((size_t)((t & 1) * 8 + g) << 16);
    u64* hwrite = hbuf + (size_t)(((t + 1) & 1) * 8 + g) * 8192;

    // ---- issue h_t fragment loads (16x dwordx4; XCD L2 if local, LLC else) ----
    frag8 af[8][2];
    const char* pb = hrd + (v << 14) + (l << 4);
    if (locl) { AF_LOAD(0, "sc0"); AF_LOAD(1, "sc0"); AF_LOAD(2, "sc0"); AF_LOAD(3, "sc0"); }
    else      { AF_LOAD(0, "sc0 sc1"); AF_LOAD(1, "sc0 sc1"); AF_LOAD(2, "sc0 sc1"); AF_LOAD(3, "sc0 sc1"); }

    // ---- issue x(t+1) prefetch (plain cached loads; consumed post-arrive) ----
    int tn = (t < 1023) ? t + 1 : 1023;  // clamp: last-iter loads are discarded
    const float* xp0 = xb0 + (size_t)tn * 128;
    const float* xp1 = xb1 + (size_t)tn * 128;
    f4 xa0n, xc0n, xa1n, xc1n;
    asm volatile(
      "global_load_dwordx4 %0, %4, off\n\t"
      "global_load_dwordx4 %1, %4, off offset:16\n\t"
      "global_load_dwordx4 %2, %5, off\n\t"
      "global_load_dwordx4 %3, %5, off offset:16"
      : "=&v"(xa0n), "=&v"(xc0n), "=&v"(xa1n), "=&v"(xc1n)
      : "v"(xp0), "v"(xp1));

    // ---- hh MFMAs in 4 chunks with counted vmcnt (20 outstanding:
    //      16 af + 4 x; chunk j needs af loads 0..4j+3 done) ----
    asm volatile("s_waitcnt vmcnt(16)"); __builtin_amdgcn_sched_barrier(0);
    HH_CHUNK(0);
    asm volatile("s_waitcnt vmcnt(12)"); __builtin_amdgcn_sched_barrier(0);
    HH_CHUNK(1);
    asm volatile("s_waitcnt vmcnt(8)");  __builtin_amdgcn_sched_barrier(0);
    HH_CHUNK(2);
    asm volatile("s_waitcnt vmcnt(4)");  __builtin_amdgcn_sched_barrier(0);
    HH_CHUNK(3);

    // ---- write K-partials to LDS (transposed, XOR-swizzled, b128) ----
#pragma unroll
    for (int bh = 0; bh < 2; ++bh) {
      int b8 = bh * 4 + lq;
#pragma unroll
      for (int rt = 0; rt < 6; ++rt) {
        int gr = rt * 16 + lm;
        xbuf[((v * 128 + gr) << 3) | (b8 ^ (gr & 7))] = acc[bh][rt];
      }
#pragma unroll
      for (int nt = 0; nt < 2; ++nt) {
        int gr = 96 + nt * 16 + lm;
        xbuf[((v * 128 + gr) << 3) | (b8 ^ (gr & 7))] = accn[bh][nt];
      }
    }
    __syncthreads();   // (1) partials visible

    // ---- gate update: thread handles 4 batches (ub0..) x 1 col (uc) ----
    int swz = (ub0 >> 2) ^ (uc & 7);
    f4 sr = zz, sz4 = zz, gn4 = zz, gin4 = zz;
#pragma unroll
    for (int vv = 0; vv < 4; ++vv) {
      sr   += xbuf[((vv * 128 + uc) << 3) | swz];
      sz4  += xbuf[((vv * 128 + 32 + uc) << 3) | swz];
      gn4  += xbuf[((vv * 128 + 64 + uc) << 3) | swz];
      gin4 += xbuf[((vv * 128 + 96 + uc) << 3) | swz];
    }
    f4 h4;
#pragma unroll
    for (int i = 0; i < 4; ++i) {
      float rr = sigmf(sr[i] + bir + bhr);
      float zg = sigmf(sz4[i] + biz + bhz);
      float nn = tanhf_(gin4[i] + bin_ + rr * (gn4[i] + bhn));
      h4[i] = (1.0f - zg) * nn + zg * hprev[i];
    }
    hprev = h4;
    __syncthreads();   // (2) xbuf reads done, safe to reuse as staging

    // ---- stage h(bf16) in LDS, repack to 8B, store to hwrite ----
    u16* sbuf = (u16*)&xbuf[0];        // [32 b][stride 40]
#pragma unroll
    for (int i = 0; i < 4; ++i) sbuf[(ub0 + i) * 40 + uc] = f2bf(h4[i]);
    __syncthreads();   // (3)
    {
      int b = tid >> 3, c0 = (tid & 7) << 2;
      u64 pk = *(const u64*)(sbuf + b * 40 + c0);
      int off = ((w * 2 + (b >> 4)) * 64 + (b & 15) + 16 * (c0 >> 3)) * 2 + ((c0 & 7) >> 2);
      if (locl) H_STORE("sc0");
      else      H_STORE("sc0 sc1");
    }
    asm volatile("s_waitcnt vmcnt(0)" ::: "memory");  // h stores at coherence point
    __syncthreads();   // (4) whole WG drained before signaling

    if (t < 1023) {
      // ---- arrive: double flag store: sc0 (fast, local L2) then sc0 sc1
      //      (guaranteed LLC copy for the escalated poll path) ----
      if (tid == 0) {
        if (locl)
          asm volatile("global_store_dword %0, %1, off sc0\n\t"
                       "global_store_dword %0, %1, off sc0 sc1"
                       :: "v"(fself), "v"((u32)(t + 1)) : "memory");
        else
          asm volatile("global_store_dword %0, %1, off sc0 sc1"
                       :: "v"(fself), "v"((u32)(t + 1)) : "memory");
      }

      // x prefetch already retired; wave0 skips its in-flight flag stores
      // (vmcnt retires in order: flags are the only outstanding ops).
      if (tid < 64) {
        if (locl) asm volatile("s_waitcnt vmcnt(2)" ::: "memory");
        else      asm volatile("s_waitcnt vmcnt(1)" ::: "memory");
      } else {
        asm volatile("s_waitcnt vmcnt(0)" ::: "memory");
      }
      __builtin_amdgcn_sched_barrier(0);

      // ---- overlapped with other WGs' arrival: EMA(t+1), pack, gi MFMAs ----
      e0a = A1 * xa0n + ALPHA * e0a; e0b = A1 * xc0n + ALPHA * e0b;
      e1a = A1 * xa1n + ALPHA * e1a; e1b = A1 * xc1n + ALPHA * e1b;
      if (t == 1022 && w == 0 && v == 0 && lq == 0) {
        // st_1 = EMA at t=1023; columns 1,2 for denorm
        st1[(g * 32 + lm) * 2 + 0] = e0a[1];
        st1[(g * 32 + lm) * 2 + 1] = e0a[2];
        st1[(g * 32 + 16 + lm) * 2 + 0] = e1a[1];
        st1[(g * 32 + 16 + lm) * 2 + 1] = e1a[2];
      }
      smf0 = pack_bf16(e0a, e0b); smf1 = pack_bf16(e1a, e1b);
      ACC_ZERO();
      IH_MFMA();

      // ---- wait: 64-lane coalesced poll; sc0 fast path, bounded escalation
      //      to sc0 sc1 (provably terminating via the LLC flag copy) ----
      if (tid < 64) {
        const u32* fp = flagbase + (tid & 31);
        u32 fv;
        int it = 0;
        while (1) {
          if (locl && it < 512) POLL_LOAD("sc0");
          else                  POLL_LOAD("sc0 sc1");
          if (__ballot(fv > (u32)t) == ~0ull) break;
          ++it;
          __builtin_amdgcn_s_sleep(1);
        }
      }
      __syncthreads();   // (5) release whole WG into next step
    }
  }
}

// out[b][o] = (h_T[b] . W_fc[o] + b_fc[o] - a*st1[b][o]) / (1-a)
__global__ void fc_kernel(const u16* __restrict__ hbuf_bf,  // parity-0 region
                          const float* __restrict__ wfc,    // [2][1024]
                          const float* __restrict__ bfc,    // [2]
                          const float* __restrict__ st1,    // [256][2]
                          float* __restrict__ out)          // [256][2]
{
  int b = blockIdx.x, t = threadIdx.x;
  int g = b >> 5, bl = b & 31, bh = bl >> 4;
  int k0 = t * 4, kb = k0 >> 5, ko = k0 & 31;
  int lane = (bl & 15) + 16 * (ko >> 3);
  const u16* hp = hbuf_bf + (size_t)g * 32768 + ((kb * 2 + bh) * 64 + lane) * 8 + (ko & 7);
  float h0 = bf2f(hp[0]), h1 = bf2f(hp[1]), h2 = bf2f(hp[2]), h3 = bf2f(hp[3]);
  float s0 = h0 * wfc[k0] + h1 * wfc[k0 + 1] + h2 * wfc[k0 + 2] + h3 * wfc[k0 + 3];
  float s1 = h0 * wfc[1024 + k0] + h1 * wfc[1024 + k0 + 1] +
             h2 * wfc[1024 + k0 + 2] + h3 * wfc[1024 + k0 + 3];
#pragma unroll
  for (int off = 32; off > 0; off >>= 1) {
    s0 += __shfl_down(s0, off);
    s1 += __shfl_down(s1, off);
  }
  __shared__ float red[8];
  if ((t & 63) == 0) { red[(t >> 6) * 2] = s0; red[(t >> 6) * 2 + 1] = s1; }
  __syncthreads();
  if (t == 0) {
    float a0 = red[0] + red[2] + red[4] + red[6] + bfc[0];
    float a1 = red[1] + red[3] + red[5] + red[7] + bfc[1];
    float inv = 1.0f / (1.0f - ALPHA);
    out[b * 2 + 0] = (a0 - ALPHA * st1[b * 2 + 0]) * inv;
    out[b * 2 + 1] = (a1 - ALPHA * st1[b * 2 + 1]) * inv;
  }
}

extern "C" void kernel_launch(void* const* d_in, const int* in_sizes, int n_in,
                              void* d_out, int out_size, void* d_ws, size_t ws_size,
                              hipStream_t stream) {
  const float* x   = (const float*)d_in[0];
  const float* Wih = (const float*)d_in[1];
  const float* Whh = (const float*)d_in[2];
  const float* bih = (const float*)d_in[3];
  const float* bhh = (const float*)d_in[4];
  const float* Wfc = (const float*)d_in[5];
  const float* bfc = (const float*)d_in[6];
  char* ws = (char*)d_ws;
  u16* whh_bf = (u16*)(ws + WHH_OFF);
  u16* wih_bf = (u16*)(ws + WIH_OFF);
  u64* hbuf   = (u64*)(ws + HBUF_OFF);
  u32* flg    = (u32*)(ws + FLG_OFF);
  u32* xcc    = (u32*)(ws + XCC_OFF);
  float* st1  = (float*)(ws + ST1_OFF);

  hipMemsetAsync(ws + HBUF_OFF, 0, ZERO_LEN, stream);
  prep_bf16<<<13824, 256, 0, stream>>>(Whh, Wih, whh_bf, wih_bf);
  gru_kernel<<<256, 256, 0, stream>>>(x, bih, bhh, whh_bf, wih_bf, hbuf, flg, xcc, st1);
  fc_kernel<<<256, 256, 0, stream>>>((const u16*)(ws + HBUF_OFF), Wfc, bfc, st1,
                                     (float*)d_out);
}

// Round 13
// 5552.479 us; speedup vs baseline: 12.4544x; 12.4544x over previous
//
#include <hip/hip_runtime.h>

typedef __attribute__((ext_vector_type(4))) float f4;
typedef __attribute__((ext_vector_type(8))) short frag8;
typedef unsigned long long u64;
typedef unsigned int u32;
typedef unsigned short u16;

#define ALPHA 0.3f

// ---- ws layout (bytes) ----
#define WHH_OFF   0ull                 // 3072*1024 bf16 = 6291456
#define WIH_OFF   6291456ull           // 3072*128 bf16  = 786432
#define HBUF_OFF  7077888ull           // 2 parities * 8 groups * 65536 = 1048576
#define FLG_OFF   8126464ull           // 8 groups * 32 u32 monotonic step flags
#define ST1_OFF   8159232ull           // 256*2 fp32 = 2048
#define XCC_OFF   8161280ull           // 256 u32 per-WG xcc-id (+1)
#define ZERO_LEN  1084416ull           // hbuf + flags + st1 + xcc

__device__ __forceinline__ u16 f2bf(float f) {
  u32 u = __float_as_uint(f);
  u32 r = (u + 0x7FFFu + ((u >> 16) & 1u)) >> 16;
  return (u16)r;
}
__device__ __forceinline__ float bf2f(u16 h) {
  return __uint_as_float(((u32)h) << 16);
}
__device__ __forceinline__ float sigmf(float x) {
  float e = __expf(-fabsf(x));
  float s = 1.0f / (1.0f + e);
  return x >= 0.f ? s : 1.0f - s;
}
__device__ __forceinline__ float tanhf_(float x) {
  float e = __expf(-2.0f * fabsf(x));
  float t = (1.0f - e) / (1.0f + e);
  return x >= 0.f ? t : -t;
}
__device__ __forceinline__ frag8 pack_bf16(f4 a, f4 b) {
  union { u16 h[8]; frag8 f; } u;
  u.h[0] = f2bf(a[0]); u.h[1] = f2bf(a[1]); u.h[2] = f2bf(a[2]); u.h[3] = f2bf(a[3]);
  u.h[4] = f2bf(b[0]); u.h[5] = f2bf(b[1]); u.h[6] = f2bf(b[2]); u.h[7] = f2bf(b[3]);
  return u.f;
}

// fp32 -> bf16 weight conversion (W_hh then W_ih), exact-sized grid.
__global__ void prep_bf16(const float* __restrict__ whh_f32,
                          const float* __restrict__ wih_f32,
                          u16* __restrict__ whh, u16* __restrict__ wih) {
  int i = blockIdx.x * 256 + threadIdx.x;
  const int nhh = 3072 * 1024;
  if (i < nhh) whh[i] = f2bf(whh_f32[i]);
  else         wih[i - nhh] = f2bf(wih_f32[i - nhh]);
}

#define ACC_ZERO() do {                                                        \
  _Pragma("unroll") for (int bh_ = 0; bh_ < 2; ++bh_) {                        \
    _Pragma("unroll") for (int rt_ = 0; rt_ < 6; ++rt_) acc[bh_][rt_] = zz;    \
    accn[bh_][0] = zz; accn[bh_][1] = zz; }                                    \
} while (0)

#define IH_MFMA() do {                                                         \
  _Pragma("unroll") for (int rt_ = 0; rt_ < 4; ++rt_) {                        \
    acc[0][rt_] = __builtin_amdgcn_mfma_f32_16x16x32_bf16(smf0, wihf[rt_], acc[0][rt_], 0, 0, 0); \
    acc[1][rt_] = __builtin_amdgcn_mfma_f32_16x16x32_bf16(smf1, wihf[rt_], acc[1][rt_], 0, 0, 0); } \
  _Pragma("unroll") for (int nt_ = 0; nt_ < 2; ++nt_) {                        \
    accn[0][nt_] = __builtin_amdgcn_mfma_f32_16x16x32_bf16(smf0, wihf[4 + nt_], accn[0][nt_], 0, 0, 0); \
    accn[1][nt_] = __builtin_amdgcn_mfma_f32_16x16x32_bf16(smf1, wihf[4 + nt_], accn[1][nt_], 0, 0, 0); } \
} while (0)

// 24 hh MFMAs consuming af[2j], af[2j+1].
#define HH_CHUNK(j) do {                                                       \
  _Pragma("unroll") for (int kk_ = 0; kk_ < 2; ++kk_) {                        \
    const int kb_ = 2 * (j) + kk_;                                             \
    _Pragma("unroll") for (int rt_ = 0; rt_ < 6; ++rt_) {                      \
      acc[0][rt_] = __builtin_amdgcn_mfma_f32_16x16x32_bf16(af[kb_][0], whhf[kb_][rt_], acc[0][rt_], 0, 0, 0); \
      acc[1][rt_] = __builtin_amdgcn_mfma_f32_16x16x32_bf16(af[kb_][1], whhf[kb_][rt_], acc[1][rt_], 0, 0, 0); } } \
} while (0)

// 4 dwordx4 coherent loads; issue order = vmcnt order. SC = cache bits:
// "sc0" (XCD-local, L2 coherence point) or "sc0 sc1" (device, LLC).
#define AF_LOAD(j, SC) asm volatile(                                           \
  "global_load_dwordx4 %0, %4, off " SC "\n\t"                                 \
  "global_load_dwordx4 %1, %4, off offset:1024 " SC "\n\t"                     \
  "global_load_dwordx4 %2, %4, off offset:2048 " SC "\n\t"                     \
  "global_load_dwordx4 %3, %4, off offset:3072 " SC                            \
  : "=&v"(af[2 * (j)][0]), "=&v"(af[2 * (j)][1]),                              \
    "=&v"(af[2 * (j) + 1][0]), "=&v"(af[2 * (j) + 1][1])                       \
  : "v"(pb + (j) * 4096))

#define H_STORE(SC) asm volatile("global_store_dwordx2 %0, %1, off " SC        \
  :: "v"(hwrite + off), "v"(pk) : "memory")
#define POLL_LOAD(SC) asm volatile("global_load_dword %0, %1, off " SC "\n\t"  \
  "s_waitcnt vmcnt(0)" : "=v"(fv) : "v"(fp) : "memory")

// Persistent GRU recurrence. 256 WGs = 8 groups (batch slices of 32) x 32 WGs
// (32 H-cols each). Group g = wg&7: group co-resident on one XCD (runtime
// verified) -> h exchange (af loads, h stores) runs sc0-only through the XCD
// L2 (proven R8: FETCH_SIZE 2.63e6 -> 9.4e4 KB).
// Flags: arrive = double store (sc0 -> L2 fresh, then sc0 sc1 -> LLC
// guarantee). Wait = nt poll (non-temporal: no-allocate, intended L0 bypass ->
// L2-fresh) for 6 iterations, then escalate to sc0 sc1 (provably terminates
// via the LLC copy). R9 lesson: sc0-only polls hit stale L0 forever; the
// escalation threshold multiplies into runtime, so keep it single-digit.
__global__ __launch_bounds__(256, 1) void gru_kernel(
    const float* __restrict__ x,       // [256][1024][128]
    const float* __restrict__ b_ih,    // [3072]
    const float* __restrict__ b_hh,    // [3072]
    const u16* __restrict__ whh,       // [3072][1024] bf16
    const u16* __restrict__ wih,       // [3072][128] bf16
    u64* __restrict__ hbuf,            // [2][8][8192] u64 (64KB per (p,g))
    u32* __restrict__ flags,           // [8][32] monotonic step counters
    u32* __restrict__ xccarr,          // [256] xcc-id + 1
    float* __restrict__ st1)           // [256][2]
{
  __shared__ f4 xbuf[4096];            // 64 KB: [4 waves][128 gr][8 b-quads] swizzled
  const int wg = blockIdx.x;
  const int g = wg & 7, w = wg >> 3;   // group spans one XCD under round-robin
  const int tid = threadIdx.x;
  const int v = tid >> 6;              // wave = K-slice of 256
  const int l = tid & 63;
  const int lm = l & 15, lq = l >> 4;

  // ---- load weight fragments into registers (persistent) ----
  frag8 whhf[8][6];
  frag8 wihf[6];
#pragma unroll
  for (int rt = 0; rt < 6; ++rt) {
    int grow = (rt >> 1) * 1024 + w * 32 + (rt & 1) * 16 + lm;  // global gate row
    wihf[rt] = *(const frag8*)(wih + grow * 128 + v * 32 + lq * 8);
#pragma unroll
    for (int kb = 0; kb < 8; ++kb)
      whhf[kb][rt] = *(const frag8*)(whh + grow * 1024 + v * 256 + kb * 32 + lq * 8);
  }

  // ---- update-phase constants ----
  const int uc = tid & 31;
  const int ub0 = (tid >> 5) << 2;
  const int colg = w * 32 + uc;
  const float bir = b_ih[colg],         bhr = b_hh[colg];
  const float biz = b_ih[1024 + colg],  bhz = b_hh[1024 + colg];
  const float bin_ = b_ih[2048 + colg], bhn = b_hh[2048 + colg];
  f4 hprev = {0.f, 0.f, 0.f, 0.f};

  const float* xb0 = x + (size_t)(g * 32 + lm) * 131072 + v * 32 + lq * 8;
  const float* xb1 = x + (size_t)(g * 32 + 16 + lm) * 131072 + v * 32 + lq * 8;

  u32* flagbase = flags + (g << 5);
  u32* fself = flagbase + w;
  const f4 zz = {0.f, 0.f, 0.f, 0.f};
  const float A1 = 1.0f - ALPHA;

  // ---- one-time XCD co-location check: barrier-style, no leader ----
  u32 myxcc;
  asm volatile("s_getreg_b32 %0, hwreg(HW_REG_XCC_ID)" : "=s"(myxcc));
  myxcc &= 15u;
  if (tid == 0) {
    u32 pub = myxcc + 1u;
    asm volatile("global_store_dword %0, %1, off sc0 sc1"
                 :: "v"(xccarr + wg), "v"(pub) : "memory");
  }
  if (tid < 64) {
    const u32* xp = xccarr + ((((tid & 31) << 3) | g));  // member (tid&31) of group g
    u32 vv;
    while (1) {
      asm volatile("global_load_dword %0, %1, off sc0 sc1\n\ts_waitcnt vmcnt(0)"
                   : "=v"(vv) : "v"(xp) : "memory");
      if (__ballot(vv != 0u) == ~0ull) break;
      __builtin_amdgcn_s_sleep(1);
    }
    u32 same = (__ballot(vv == myxcc + 1u) == ~0ull) ? 1u : 0u;
    if (tid == 0) *(volatile u32*)&xbuf[0] = same;
  }
  __syncthreads();
  const bool locl = (*(volatile u32*)&xbuf[0]) != 0u;
  __syncthreads();   // xbuf[0] consumed before first loop LDS write

  // ---- prologue: EMA(0) = x(0); pack; gi(0) MFMAs ----
  f4 e0a = *(const f4*)xb0, e0b = *(const f4*)(xb0 + 4);
  f4 e1a = *(const f4*)xb1, e1b = *(const f4*)(xb1 + 4);
  frag8 smf0 = pack_bf16(e0a, e0b), smf1 = pack_bf16(e1a, e1b);
  f4 acc[2][6], accn[2][2];
  ACC_ZERO();
  IH_MFMA();

#pragma unroll 1
  for (int t = 0; t < 1024; ++t) {
    const char* hrd = (const char*)hbuf + ((size_t)((t & 1) * 8 + g) << 16);
    u64* hwrite = hbuf + (size_t)(((t + 1) & 1) * 8 + g) * 8192;

    // ---- issue h_t fragment loads (16x dwordx4; XCD L2 if local, LLC else) ----
    frag8 af[8][2];
    const char* pb = hrd + (v << 14) + (l << 4);
    if (locl) { AF_LOAD(0, "sc0"); AF_LOAD(1, "sc0"); AF_LOAD(2, "sc0"); AF_LOAD(3, "sc0"); }
    else      { AF_LOAD(0, "sc0 sc1"); AF_LOAD(1, "sc0 sc1"); AF_LOAD(2, "sc0 sc1"); AF_LOAD(3, "sc0 sc1"); }

    // ---- issue x(t+1) prefetch (plain cached loads; consumed post-arrive) ----
    int tn = (t < 1023) ? t + 1 : 1023;  // clamp: last-iter loads are discarded
    const float* xp0 = xb0 + (size_t)tn * 128;
    const float* xp1 = xb1 + (size_t)tn * 128;
    f4 xa0n, xc0n, xa1n, xc1n;
    asm volatile(
      "global_load_dwordx4 %0, %4, off\n\t"
      "global_load_dwordx4 %1, %4, off offset:16\n\t"
      "global_load_dwordx4 %2, %5, off\n\t"
      "global_load_dwordx4 %3, %5, off offset:16"
      : "=&v"(xa0n), "=&v"(xc0n), "=&v"(xa1n), "=&v"(xc1n)
      : "v"(xp0), "v"(xp1));

    // ---- hh MFMAs in 4 chunks with counted vmcnt (20 outstanding:
    //      16 af + 4 x; chunk j needs af loads 0..4j+3 done) ----
    asm volatile("s_waitcnt vmcnt(16)"); __builtin_amdgcn_sched_barrier(0);
    HH_CHUNK(0);
    asm volatile("s_waitcnt vmcnt(12)"); __builtin_amdgcn_sched_barrier(0);
    HH_CHUNK(1);
    asm volatile("s_waitcnt vmcnt(8)");  __builtin_amdgcn_sched_barrier(0);
    HH_CHUNK(2);
    asm volatile("s_waitcnt vmcnt(4)");  __builtin_amdgcn_sched_barrier(0);
    HH_CHUNK(3);

    // ---- write K-partials to LDS (transposed, XOR-swizzled, b128) ----
#pragma unroll
    for (int bh = 0; bh < 2; ++bh) {
      int b8 = bh * 4 + lq;
#pragma unroll
      for (int rt = 0; rt < 6; ++rt) {
        int gr = rt * 16 + lm;
        xbuf[((v * 128 + gr) << 3) | (b8 ^ (gr & 7))] = acc[bh][rt];
      }
#pragma unroll
      for (int nt = 0; nt < 2; ++nt) {
        int gr = 96 + nt * 16 + lm;
        xbuf[((v * 128 + gr) << 3) | (b8 ^ (gr & 7))] = accn[bh][nt];
      }
    }
    __syncthreads();   // (1) partials visible

    // ---- gate update: thread handles 4 batches (ub0..) x 1 col (uc) ----
    int swz = (ub0 >> 2) ^ (uc & 7);
    f4 sr = zz, sz4 = zz, gn4 = zz, gin4 = zz;
#pragma unroll
    for (int vv = 0; vv < 4; ++vv) {
      sr   += xbuf[((vv * 128 + uc) << 3) | swz];
      sz4  += xbuf[((vv * 128 + 32 + uc) << 3) | swz];
      gn4  += xbuf[((vv * 128 + 64 + uc) << 3) | swz];
      gin4 += xbuf[((vv * 128 + 96 + uc) << 3) | swz];
    }
    f4 h4;
#pragma unroll
    for (int i = 0; i < 4; ++i) {
      float rr = sigmf(sr[i] + bir + bhr);
      float zg = sigmf(sz4[i] + biz + bhz);
      float nn = tanhf_(gin4[i] + bin_ + rr * (gn4[i] + bhn));
      h4[i] = (1.0f - zg) * nn + zg * hprev[i];
    }
    hprev = h4;
    __syncthreads();   // (2) xbuf reads done, safe to reuse as staging

    // ---- stage h(bf16) in LDS, repack to 8B, store to hwrite ----
    u16* sbuf = (u16*)&xbuf[0];        // [32 b][stride 40]
#pragma unroll
    for (int i = 0; i < 4; ++i) sbuf[(ub0 + i) * 40 + uc] = f2bf(h4[i]);
    __syncthreads();   // (3)
    {
      int b = tid >> 3, c0 = (tid & 7) << 2;
      u64 pk = *(const u64*)(sbuf + b * 40 + c0);
      int off = ((w * 2 + (b >> 4)) * 64 + (b & 15) + 16 * (c0 >> 3)) * 2 + ((c0 & 7) >> 2);
      if (locl) H_STORE("sc0");
      else      H_STORE("sc0 sc1");
    }
    asm volatile("s_waitcnt vmcnt(0)" ::: "memory");  // h stores at coherence point
    __syncthreads();   // (4) whole WG drained before signaling

    if (t < 1023) {
      // ---- arrive: double flag store: sc0 (fast, local L2) then sc0 sc1
      //      (guaranteed LLC copy for the escalated poll path) ----
      if (tid == 0) {
        if (locl)
          asm volatile("global_store_dword %0, %1, off sc0\n\t"
                       "global_store_dword %0, %1, off sc0 sc1"
                       :: "v"(fself), "v"((u32)(t + 1)) : "memory");
        else
          asm volatile("global_store_dword %0, %1, off sc0 sc1"
                       :: "v"(fself), "v"((u32)(t + 1)) : "memory");
      }

      // x prefetch already retired; wave0 skips its in-flight flag stores
      // (vmcnt retires in order: flags are the only outstanding ops).
      if (tid < 64) {
        if (locl) asm volatile("s_waitcnt vmcnt(2)" ::: "memory");
        else      asm volatile("s_waitcnt vmcnt(1)" ::: "memory");
      } else {
        asm volatile("s_waitcnt vmcnt(0)" ::: "memory");
      }
      __builtin_amdgcn_sched_barrier(0);

      // ---- overlapped with other WGs' arrival: EMA(t+1), pack, gi MFMAs ----
      e0a = A1 * xa0n + ALPHA * e0a; e0b = A1 * xc0n + ALPHA * e0b;
      e1a = A1 * xa1n + ALPHA * e1a; e1b = A1 * xc1n + ALPHA * e1b;
      if (t == 1022 && w == 0 && v == 0 && lq == 0) {
        // st_1 = EMA at t=1023; columns 1,2 for denorm
        st1[(g * 32 + lm) * 2 + 0] = e0a[1];
        st1[(g * 32 + lm) * 2 + 1] = e0a[2];
        st1[(g * 32 + 16 + lm) * 2 + 0] = e1a[1];
        st1[(g * 32 + 16 + lm) * 2 + 1] = e1a[2];
      }
      smf0 = pack_bf16(e0a, e0b); smf1 = pack_bf16(e1a, e1b);
      ACC_ZERO();
      IH_MFMA();

      // ---- wait: 64-lane coalesced poll; nt fast path (no-allocate, L0
      //      bypass -> L2-fresh), 6-iter bounded escalation to sc0 sc1 ----
      if (tid < 64) {
        const u32* fp = flagbase + (tid & 31);
        u32 fv;
        int it = 0;
        while (1) {
          if (locl && it < 6) POLL_LOAD("nt");
          else                POLL_LOAD("sc0 sc1");
          if (__ballot(fv > (u32)t) == ~0ull) break;
          ++it;
          __builtin_amdgcn_s_sleep(1);
        }
      }
      __syncthreads();   // (5) release whole WG into next step
    }
  }
}

// out[b][o] = (h_T[b] . W_fc[o] + b_fc[o] - a*st1[b][o]) / (1-a)
__global__ void fc_kernel(const u16* __restrict__ hbuf_bf,  // parity-0 region
                          const float* __restrict__ wfc,    // [2][1024]
                          const float* __restrict__ bfc,    // [2]
                          const float* __restrict__ st1,    // [256][2]
                          float* __restrict__ out)          // [256][2]
{
  int b = blockIdx.x, t = threadIdx.x;
  int g = b >> 5, bl = b & 31, bh = bl >> 4;
  int k0 = t * 4, kb = k0 >> 5, ko = k0 & 31;
  int lane = (bl & 15) + 16 * (ko >> 3);
  const u16* hp = hbuf_bf + (size_t)g * 32768 + ((kb * 2 + bh) * 64 + lane) * 8 + (ko & 7);
  float h0 = bf2f(hp[0]), h1 = bf2f(hp[1]), h2 = bf2f(hp[2]), h3 = bf2f(hp[3]);
  float s0 = h0 * wfc[k0] + h1 * wfc[k0 + 1] + h2 * wfc[k0 + 2] + h3 * wfc[k0 + 3];
  float s1 = h0 * wfc[1024 + k0] + h1 * wfc[1024 + k0 + 1] +
             h2 * wfc[1024 + k0 + 2] + h3 * wfc[1024 + k0 + 3];
#pragma unroll
  for (int off = 32; off > 0; off >>= 1) {
    s0 += __shfl_down(s0, off);
    s1 += __shfl_down(s1, off);
  }
  __shared__ float red[8];
  if ((t & 63) == 0) { red[(t >> 6) * 2] = s0; red[(t >> 6) * 2 + 1] = s1; }
  __syncthreads();
  if (t == 0) {
    float a0 = red[0] + red[2] + red[4] + red[6] + bfc[0];
    float a1 = red[1] + red[3] + red[5] + red[7] + bfc[1];
    float inv = 1.0f / (1.0f - ALPHA);
    out[b * 2 + 0] = (a0 - ALPHA * st1[b * 2 + 0]) * inv;
    out[b * 2 + 1] = (a1 - ALPHA * st1[b * 2 + 1]) * inv;
  }
}

extern "C" void kernel_launch(void* const* d_in, const int* in_sizes, int n_in,
                              void* d_out, int out_size, void* d_ws, size_t ws_size,
                              hipStream_t stream) {
  const float* x   = (const float*)d_in[0];
  const float* Wih = (const float*)d_in[1];
  const float* Whh = (const float*)d_in[2];
  const float* bih = (const float*)d_in[3];
  const float* bhh = (const float*)d_in[4];
  const float* Wfc = (const float*)d_in[5];
  const float* bfc = (const float*)d_in[6];
  char* ws = (char*)d_ws;
  u16* whh_bf = (u16*)(ws + WHH_OFF);
  u16* wih_bf = (u16*)(ws + WIH_OFF);
  u64* hbuf   = (u64*)(ws + HBUF_OFF);
  u32* flg    = (u32*)(ws + FLG_OFF);
  u32* xcc    = (u32*)(ws + XCC_OFF);
  float* st1  = (float*)(ws + ST1_OFF);

  hipMemsetAsync(ws + HBUF_OFF, 0, ZERO_LEN, stream);
  prep_bf16<<<13824, 256, 0, stream>>>(Whh, Wih, whh_bf, wih_bf);
  gru_kernel<<<256, 256, 0, stream>>>(x, bih, bhh, whh_bf, wih_bf, hbuf, flg, xcc, st1);
  fc_kernel<<<256, 256, 0, stream>>>((const u16*)(ws + HBUF_OFF), Wfc, bfc, st1,
                                     (float*)d_out);
}

// Round 14
// 5484.803 us; speedup vs baseline: 12.6080x; 1.0123x over previous
//
#include <hip/hip_runtime.h>

typedef __attribute__((ext_vector_type(4))) float f4;
typedef __attribute__((ext_vector_type(8))) short frag8;
typedef unsigned long long u64;
typedef unsigned int u32;
typedef unsigned short u16;

#define ALPHA 0.3f

// ---- ws layout (bytes) ----
#define WHH_OFF   0ull                 // 3072*1024 bf16 = 6291456
#define WIH_OFF   6291456ull           // 3072*128 bf16  = 786432
#define HBUF_OFF  7077888ull           // 2 parities * 8 groups * 65536 = 1048576
#define FLG_OFF   8126464ull           // 8 groups * 32 u32 monotonic step flags
#define ST1_OFF   8159232ull           // 256*2 fp32 = 2048
#define XCC_OFF   8161280ull           // 256 u32 per-WG xcc-id (+1)
#define ZERO_LEN  1084416ull           // hbuf + flags + st1 + xcc

__device__ __forceinline__ u16 f2bf(float f) {
  u32 u = __float_as_uint(f);
  u32 r = (u + 0x7FFFu + ((u >> 16) & 1u)) >> 16;
  return (u16)r;
}
__device__ __forceinline__ float bf2f(u16 h) {
  return __uint_as_float(((u32)h) << 16);
}
__device__ __forceinline__ float sigmf(float x) {
  float e = __expf(-fabsf(x));
  float s = 1.0f / (1.0f + e);
  return x >= 0.f ? s : 1.0f - s;
}
__device__ __forceinline__ float tanhf_(float x) {
  float e = __expf(-2.0f * fabsf(x));
  float t = (1.0f - e) / (1.0f + e);
  return x >= 0.f ? t : -t;
}
__device__ __forceinline__ frag8 pack_bf16(f4 a, f4 b) {
  union { u16 h[8]; frag8 f; } u;
  u.h[0] = f2bf(a[0]); u.h[1] = f2bf(a[1]); u.h[2] = f2bf(a[2]); u.h[3] = f2bf(a[3]);
  u.h[4] = f2bf(b[0]); u.h[5] = f2bf(b[1]); u.h[6] = f2bf(b[2]); u.h[7] = f2bf(b[3]);
  return u.f;
}

// fp32 -> bf16 weight conversion (W_hh then W_ih), exact-sized grid.
__global__ void prep_bf16(const float* __restrict__ whh_f32,
                          const float* __restrict__ wih_f32,
                          u16* __restrict__ whh, u16* __restrict__ wih) {
  int i = blockIdx.x * 256 + threadIdx.x;
  const int nhh = 3072 * 1024;
  if (i < nhh) whh[i] = f2bf(whh_f32[i]);
  else         wih[i - nhh] = f2bf(wih_f32[i - nhh]);
}

#define ACC_ZERO() do {                                                        \
  _Pragma("unroll") for (int bh_ = 0; bh_ < 2; ++bh_) {                        \
    _Pragma("unroll") for (int rt_ = 0; rt_ < 6; ++rt_) acc[bh_][rt_] = zz;    \
    accn[bh_][0] = zz; accn[bh_][1] = zz; }                                    \
} while (0)

#define IH_MFMA() do {                                                         \
  _Pragma("unroll") for (int rt_ = 0; rt_ < 4; ++rt_) {                        \
    acc[0][rt_] = __builtin_amdgcn_mfma_f32_16x16x32_bf16(smf0, wihf[rt_], acc[0][rt_], 0, 0, 0); \
    acc[1][rt_] = __builtin_amdgcn_mfma_f32_16x16x32_bf16(smf1, wihf[rt_], acc[1][rt_], 0, 0, 0); } \
  _Pragma("unroll") for (int nt_ = 0; nt_ < 2; ++nt_) {                        \
    accn[0][nt_] = __builtin_amdgcn_mfma_f32_16x16x32_bf16(smf0, wihf[4 + nt_], accn[0][nt_], 0, 0, 0); \
    accn[1][nt_] = __builtin_amdgcn_mfma_f32_16x16x32_bf16(smf1, wihf[4 + nt_], accn[1][nt_], 0, 0, 0); } \
} while (0)

// 24 hh MFMAs consuming af[2j], af[2j+1].
#define HH_CHUNK(j) do {                                                       \
  _Pragma("unroll") for (int kk_ = 0; kk_ < 2; ++kk_) {                        \
    const int kb_ = 2 * (j) + kk_;                                             \
    _Pragma("unroll") for (int rt_ = 0; rt_ < 6; ++rt_) {                      \
      acc[0][rt_] = __builtin_amdgcn_mfma_f32_16x16x32_bf16(af[kb_][0], whhf[kb_][rt_], acc[0][rt_], 0, 0, 0); \
      acc[1][rt_] = __builtin_amdgcn_mfma_f32_16x16x32_bf16(af[kb_][1], whhf[kb_][rt_], acc[1][rt_], 0, 0, 0); } } \
} while (0)

// 4 dwordx4 coherent loads; issue order = vmcnt order. SC = cache bits:
// "sc0" (XCD-local, L2 coherence point) or "sc0 sc1" (device, LLC).
#define AF_LOAD(j, SC) asm volatile(                                           \
  "global_load_dwordx4 %0, %4, off " SC "\n\t"                                 \
  "global_load_dwordx4 %1, %4, off offset:1024 " SC "\n\t"                     \
  "global_load_dwordx4 %2, %4, off offset:2048 " SC "\n\t"                     \
  "global_load_dwordx4 %3, %4, off offset:3072 " SC                            \
  : "=&v"(af[2 * (j)][0]), "=&v"(af[2 * (j)][1]),                              \
    "=&v"(af[2 * (j) + 1][0]), "=&v"(af[2 * (j) + 1][1])                       \
  : "v"(pb + (j) * 4096))

#define H_STORE(SC) asm volatile("global_store_dwordx2 %0, %1, off " SC        \
  :: "v"(hwrite + off), "v"(pk) : "memory")

// Persistent GRU recurrence. 256 WGs = 8 groups (batch slices of 32) x 32 WGs
// (32 H-cols each). Group g = wg&7: group co-resident on one XCD (runtime
// verified) -> h exchange (af loads, h stores) via sc0 through the XCD L2
// (proven R8: FETCH_SIZE 2.63e6 -> 9.4e4 KB). Flags device scope only (R9/R13
// closed the local-flag line: sc0 and nt polls both serve stale data).
//
// Fine-grained sync (this round): hbuf region [2048w, 2048w+2048) belongs to
// writer w; wave v's AF_LOAD(j) covers exactly writers {8v+2j, 8v+2j+1}. So:
//  - loop top: wave v blocks only on flags[8v..8v+7] >= t  (its 8 writers)
//  - global all-32 check (gates h-store overwrite) issued NON-BLOCKING at
//    step start, validated just before h-store (~2500 cyc later -> hidden),
//    rare blocking re-poll fallback. No end-of-step barrier; skew absorbed.
__global__ __launch_bounds__(256, 1) void gru_kernel(
    const float* __restrict__ x,       // [256][1024][128]
    const float* __restrict__ b_ih,    // [3072]
    const float* __restrict__ b_hh,    // [3072]
    const u16* __restrict__ whh,       // [3072][1024] bf16
    const u16* __restrict__ wih,       // [3072][128] bf16
    u64* __restrict__ hbuf,            // [2][8][8192] u64 (64KB per (p,g))
    u32* __restrict__ flags,           // [8][32] monotonic step counters
    u32* __restrict__ xccarr,          // [256] xcc-id + 1
    float* __restrict__ st1)           // [256][2]
{
  __shared__ f4 xbuf[4096];            // 64 KB: [4 waves][128 gr][8 b-quads] swizzled
  const int wg = blockIdx.x;
  const int g = wg & 7, w = wg >> 3;   // group spans one XCD under round-robin
  const int tid = threadIdx.x;
  const int v = tid >> 6;              // wave = K-slice of 256
  const int l = tid & 63;
  const int lm = l & 15, lq = l >> 4;

  // ---- load weight fragments into registers (persistent) ----
  frag8 whhf[8][6];
  frag8 wihf[6];
#pragma unroll
  for (int rt = 0; rt < 6; ++rt) {
    int grow = (rt >> 1) * 1024 + w * 32 + (rt & 1) * 16 + lm;  // global gate row
    wihf[rt] = *(const frag8*)(wih + grow * 128 + v * 32 + lq * 8);
#pragma unroll
    for (int kb = 0; kb < 8; ++kb)
      whhf[kb][rt] = *(const frag8*)(whh + grow * 1024 + v * 256 + kb * 32 + lq * 8);
  }

  // ---- update-phase constants ----
  const int uc = tid & 31;
  const int ub0 = (tid >> 5) << 2;
  const int colg = w * 32 + uc;
  const float bir = b_ih[colg],         bhr = b_hh[colg];
  const float biz = b_ih[1024 + colg],  bhz = b_hh[1024 + colg];
  const float bin_ = b_ih[2048 + colg], bhn = b_hh[2048 + colg];
  f4 hprev = {0.f, 0.f, 0.f, 0.f};

  const float* xb0 = x + (size_t)(g * 32 + lm) * 131072 + v * 32 + lq * 8;
  const float* xb1 = x + (size_t)(g * 32 + 16 + lm) * 131072 + v * 32 + lq * 8;

  u32* flagbase = flags + (g << 5);
  u32* fself = flagbase + w;
  const u32* fp8 = flagbase + 8 * v + (l & 7);   // this wave's 8 writers
  const u32* gp  = flagbase + (l & 31);          // global check (2x dup)
  const f4 zz = {0.f, 0.f, 0.f, 0.f};
  const float A1 = 1.0f - ALPHA;

  // ---- one-time XCD co-location check: barrier-style, no leader ----
  u32 myxcc;
  asm volatile("s_getreg_b32 %0, hwreg(HW_REG_XCC_ID)" : "=s"(myxcc));
  myxcc &= 15u;
  if (tid == 0) {
    u32 pub = myxcc + 1u;
    asm volatile("global_store_dword %0, %1, off sc0 sc1"
                 :: "v"(xccarr + wg), "v"(pub) : "memory");
  }
  if (tid < 64) {
    const u32* xp = xccarr + ((((tid & 31) << 3) | g));  // member (tid&31) of group g
    u32 vv;
    while (1) {
      asm volatile("global_load_dword %0, %1, off sc0 sc1\n\ts_waitcnt vmcnt(0)"
                   : "=v"(vv) : "v"(xp) : "memory");
      if (__ballot(vv != 0u) == ~0ull) break;
      __builtin_amdgcn_s_sleep(1);
    }
    u32 same = (__ballot(vv == myxcc + 1u) == ~0ull) ? 1u : 0u;
    if (tid == 0) *(volatile u32*)&xbuf[0] = same;
  }
  __syncthreads();
  const bool locl = (*(volatile u32*)&xbuf[0]) != 0u;
  __syncthreads();   // xbuf[0] consumed before first loop LDS write

  // ---- prologue: EMA(0) = x(0); pack; gi(0) MFMAs ----
  f4 e0a = *(const f4*)xb0, e0b = *(const f4*)(xb0 + 4);
  f4 e1a = *(const f4*)xb1, e1b = *(const f4*)(xb1 + 4);
  frag8 smf0 = pack_bf16(e0a, e0b), smf1 = pack_bf16(e1a, e1b);
  f4 acc[2][6], accn[2][2];
  ACC_ZERO();
  IH_MFMA();

#pragma unroll 1
  for (int t = 0; t < 1024; ++t) {
    const char* hrd = (const char*)hbuf + ((size_t)((t & 1) * 8 + g) << 16);
    u64* hwrite = hbuf + (size_t)(((t + 1) & 1) * 8 + g) * 8192;

    // ---- loop top: wave blocks on ITS 8 writers only (F >= t) ----
    if (t) {
      u32 fv;
      while (1) {
        asm volatile("global_load_dword %0, %1, off sc0 sc1\n\ts_waitcnt vmcnt(0)"
                     : "=v"(fv) : "v"(fp8) : "memory");
        if (__ballot(fv >= (u32)t) == ~0ull) break;
        __builtin_amdgcn_s_sleep(1);
      }
    }

    // ---- issue global all-32 check NON-BLOCKING (validated pre-h-store;
    //      issued first so vmcnt waits below stay 16/12/8/4) ----
    u32 gv;
    asm volatile("global_load_dword %0, %1, off sc0 sc1" : "=v"(gv) : "v"(gp));

    // ---- issue h_t fragment loads (16x dwordx4; XCD L2 if local, LLC else) ----
    frag8 af[8][2];
    const char* pb = hrd + (v << 14) + (l << 4);
    if (locl) { AF_LOAD(0, "sc0"); AF_LOAD(1, "sc0"); AF_LOAD(2, "sc0"); AF_LOAD(3, "sc0"); }
    else      { AF_LOAD(0, "sc0 sc1"); AF_LOAD(1, "sc0 sc1"); AF_LOAD(2, "sc0 sc1"); AF_LOAD(3, "sc0 sc1"); }

    // ---- issue x(t+1) prefetch (plain cached loads; consumed post-sync4) ----
    int tn = (t < 1023) ? t + 1 : 1023;  // clamp: last-iter loads are discarded
    const float* xp0 = xb0 + (size_t)tn * 128;
    const float* xp1 = xb1 + (size_t)tn * 128;
    f4 xa0n, xc0n, xa1n, xc1n;
    asm volatile(
      "global_load_dwordx4 %0, %4, off\n\t"
      "global_load_dwordx4 %1, %4, off offset:16\n\t"
      "global_load_dwordx4 %2, %5, off\n\t"
      "global_load_dwordx4 %3, %5, off offset:16"
      : "=&v"(xa0n), "=&v"(xc0n), "=&v"(xa1n), "=&v"(xc1n)
      : "v"(xp0), "v"(xp1));

    // ---- hh MFMAs in 4 chunks with counted vmcnt (21 outstanding:
    //      1 gv + 16 af + 4 x; vmcnt(16-4j) retires gv + af[0..4j+3]) ----
    asm volatile("s_waitcnt vmcnt(16)"); __builtin_amdgcn_sched_barrier(0);
    HH_CHUNK(0);
    asm volatile("s_waitcnt vmcnt(12)"); __builtin_amdgcn_sched_barrier(0);
    HH_CHUNK(1);
    asm volatile("s_waitcnt vmcnt(8)");  __builtin_amdgcn_sched_barrier(0);
    HH_CHUNK(2);
    asm volatile("s_waitcnt vmcnt(4)");  __builtin_amdgcn_sched_barrier(0);
    HH_CHUNK(3);

    // ---- write K-partials to LDS (transposed, XOR-swizzled, b128) ----
#pragma unroll
    for (int bh = 0; bh < 2; ++bh) {
      int b8 = bh * 4 + lq;
#pragma unroll
      for (int rt = 0; rt < 6; ++rt) {
        int gr = rt * 16 + lm;
        xbuf[((v * 128 + gr) << 3) | (b8 ^ (gr & 7))] = acc[bh][rt];
      }
#pragma unroll
      for (int nt = 0; nt < 2; ++nt) {
        int gr = 96 + nt * 16 + lm;
        xbuf[((v * 128 + gr) << 3) | (b8 ^ (gr & 7))] = accn[bh][nt];
      }
    }
    __syncthreads();   // (1) partials visible

    // ---- gate update: thread handles 4 batches (ub0..) x 1 col (uc) ----
    int swz = (ub0 >> 2) ^ (uc & 7);
    f4 sr = zz, sz4 = zz, gn4 = zz, gin4 = zz;
#pragma unroll
    for (int vv = 0; vv < 4; ++vv) {
      sr   += xbuf[((vv * 128 + uc) << 3) | swz];
      sz4  += xbuf[((vv * 128 + 32 + uc) << 3) | swz];
      gn4  += xbuf[((vv * 128 + 64 + uc) << 3) | swz];
      gin4 += xbuf[((vv * 128 + 96 + uc) << 3) | swz];
    }
    f4 h4;
#pragma unroll
    for (int i = 0; i < 4; ++i) {
      float rr = sigmf(sr[i] + bir + bhr);
      float zg = sigmf(sz4[i] + biz + bhz);
      float nn = tanhf_(gin4[i] + bin_ + rr * (gn4[i] + bhn));
      h4[i] = (1.0f - zg) * nn + zg * hprev[i];
    }
    hprev = h4;
    __syncthreads();   // (2) xbuf reads done, safe to reuse as staging

    // ---- stage h(bf16) in LDS, repack to 8B ----
    u16* sbuf = (u16*)&xbuf[0];        // [32 b][stride 40]
#pragma unroll
    for (int i = 0; i < 4; ++i) sbuf[(ub0 + i) * 40 + uc] = f2bf(h4[i]);
    __syncthreads();   // (3)

    // ---- validate global check (gv retired at chunk0's vmcnt; hidden).
    //      h-store overwrites the buffer read at step t-1: need all F >= t. ----
    if (__ballot(gv >= (u32)t) != ~0ull) {
      u32 fv;
      while (1) {
        asm volatile("global_load_dword %0, %1, off sc0 sc1\n\ts_waitcnt vmcnt(0)"
                     : "=v"(fv) : "v"(gp) : "memory");
        if (__ballot(fv >= (u32)t) == ~0ull) break;
        __builtin_amdgcn_s_sleep(1);
      }
    }

    // ---- store h to hwrite ----
    {
      int b = tid >> 3, c0 = (tid & 7) << 2;
      u64 pk = *(const u64*)(sbuf + b * 40 + c0);
      int off = ((w * 2 + (b >> 4)) * 64 + (b & 15) + 16 * (c0 >> 3)) * 2 + ((c0 & 7) >> 2);
      if (locl) H_STORE("sc0");
      else      H_STORE("sc0 sc1");
    }
    asm volatile("s_waitcnt vmcnt(0)" ::: "memory");  // h + x drained
    __syncthreads();   // (4) whole WG drained before signaling

    if (t < 1023) {
      // ---- arrive: single device-scope flag store (wave 3 carries it) ----
      if (tid == 192)
        asm volatile("global_store_dword %0, %1, off sc0 sc1"
                     :: "v"(fself), "v"((u32)(t + 1)) : "memory");
      __builtin_amdgcn_sched_barrier(0);

      // ---- overlapped with other WGs' arrival: EMA(t+1), pack, gi MFMAs ----
      // (x retired at the pre-sync4 vmcnt(0); no extra wait needed)
      e0a = A1 * xa0n + ALPHA * e0a; e0b = A1 * xc0n + ALPHA * e0b;
      e1a = A1 * xa1n + ALPHA * e1a; e1b = A1 * xc1n + ALPHA * e1b;
      if (t == 1022 && w == 0 && v == 0 && lq == 0) {
        // st_1 = EMA at t=1023; columns 1,2 for denorm
        st1[(g * 32 + lm) * 2 + 0] = e0a[1];
        st1[(g * 32 + lm) * 2 + 1] = e0a[2];
        st1[(g * 32 + 16 + lm) * 2 + 0] = e1a[1];
        st1[(g * 32 + 16 + lm) * 2 + 1] = e1a[2];
      }
      smf0 = pack_bf16(e0a, e0b); smf1 = pack_bf16(e1a, e1b);
      ACC_ZERO();
      IH_MFMA();
      // no end-of-step wait: next loop top blocks on own-8 flags only
    }
  }
}

// out[b][o] = (h_T[b] . W_fc[o] + b_fc[o] - a*st1[b][o]) / (1-a)
__global__ void fc_kernel(const u16* __restrict__ hbuf_bf,  // parity-0 region
                          const float* __restrict__ wfc,    // [2][1024]
                          const float* __restrict__ bfc,    // [2]
                          const float* __restrict__ st1,    // [256][2]
                          float* __restrict__ out)          // [256][2]
{
  int b = blockIdx.x, t = threadIdx.x;
  int g = b >> 5, bl = b & 31, bh = bl >> 4;
  int k0 = t * 4, kb = k0 >> 5, ko = k0 & 31;
  int lane = (bl & 15) + 16 * (ko >> 3);
  const u16* hp = hbuf_bf + (size_t)g * 32768 + ((kb * 2 + bh) * 64 + lane) * 8 + (ko & 7);
  float h0 = bf2f(hp[0]), h1 = bf2f(hp[1]), h2 = bf2f(hp[2]), h3 = bf2f(hp[3]);
  float s0 = h0 * wfc[k0] + h1 * wfc[k0 + 1] + h2 * wfc[k0 + 2] + h3 * wfc[k0 + 3];
  float s1 = h0 * wfc[1024 + k0] + h1 * wfc[1024 + k0 + 1] +
             h2 * wfc[1024 + k0 + 2] + h3 * wfc[1024 + k0 + 3];
#pragma unroll
  for (int off = 32; off > 0; off >>= 1) {
    s0 += __shfl_down(s0, off);
    s1 += __shfl_down(s1, off);
  }
  __shared__ float red[8];
  if ((t & 63) == 0) { red[(t >> 6) * 2] = s0; red[(t >> 6) * 2 + 1] = s1; }
  __syncthreads();
  if (t == 0) {
    float a0 = red[0] + red[2] + red[4] + red[6] + bfc[0];
    float a1 = red[1] + red[3] + red[5] + red[7] + bfc[1];
    float inv = 1.0f / (1.0f - ALPHA);
    out[b * 2 + 0] = (a0 - ALPHA * st1[b * 2 + 0]) * inv;
    out[b * 2 + 1] = (a1 - ALPHA * st1[b * 2 + 1]) * inv;
  }
}

extern "C" void kernel_launch(void* const* d_in, const int* in_sizes, int n_in,
                              void* d_out, int out_size, void* d_ws, size_t ws_size,
                              hipStream_t stream) {
  const float* x   = (const float*)d_in[0];
  const float* Wih = (const float*)d_in[1];
  const float* Whh = (const float*)d_in[2];
  const float* bih = (const float*)d_in[3];
  const float* bhh = (const float*)d_in[4];
  const float* Wfc = (const float*)d_in[5];
  const float* bfc = (const float*)d_in[6];
  char* ws = (char*)d_ws;
  u16* whh_bf = (u16*)(ws + WHH_OFF);
  u16* wih_bf = (u16*)(ws + WIH_OFF);
  u64* hbuf   = (u64*)(ws + HBUF_OFF);
  u32* flg    = (u32*)(ws + FLG_OFF);
  u32* xcc    = (u32*)(ws + XCC_OFF);
  float* st1  = (float*)(ws + ST1_OFF);

  hipMemsetAsync(ws + HBUF_OFF, 0, ZERO_LEN, stream);
  prep_bf16<<<13824, 256, 0, stream>>>(Whh, Wih, whh_bf, wih_bf);
  gru_kernel<<<256, 256, 0, stream>>>(x, bih, bhh, whh_bf, wih_bf, hbuf, flg, xcc, st1);
  fc_kernel<<<256, 256, 0, stream>>>((const u16*)(ws + HBUF_OFF), Wfc, bfc, st1,
                                     (float*)d_out);
}

// Round 15
// 3839.754 us; speedup vs baseline: 18.0097x; 1.4284x over previous
//
#include <hip/hip_runtime.h>

typedef __attribute__((ext_vector_type(4))) float f4;
typedef __attribute__((ext_vector_type(8))) short frag8;
typedef unsigned long long u64;
typedef unsigned int u32;
typedef unsigned short u16;

#define ALPHA 0.3f

// ---- ws layout (bytes) ----
#define WHH_OFF   0ull                 // 3072*1024 bf16 = 6291456
#define WIH_OFF   6291456ull           // 3072*128 bf16  = 786432
#define HBUF_OFF  7077888ull           // 2 parities * 8 groups * 65536 = 1048576
#define FLG_OFF   8126464ull           // 8 groups * 32 u32 monotonic step flags
#define ST1_OFF   8159232ull           // 256*2 fp32 = 2048
#define XCC_OFF   8161280ull           // 256 u32 per-WG xcc-id (+1)
#define ZERO_LEN  1084416ull           // hbuf + flags + st1 + xcc

__device__ __forceinline__ u16 f2bf(float f) {
  u32 u = __float_as_uint(f);
  u32 r = (u + 0x7FFFu + ((u >> 16) & 1u)) >> 16;
  return (u16)r;
}
__device__ __forceinline__ float bf2f(u16 h) {
  return __uint_as_float(((u32)h) << 16);
}
__device__ __forceinline__ float sigmf(float x) {
  float e = __expf(-fabsf(x));
  float s = 1.0f / (1.0f + e);
  return x >= 0.f ? s : 1.0f - s;
}
__device__ __forceinline__ float tanhf_(float x) {
  float e = __expf(-2.0f * fabsf(x));
  float t = (1.0f - e) / (1.0f + e);
  return x >= 0.f ? t : -t;
}
// RNE packed f32->bf16 (T12: no builtin on gfx950; 4 insts for 16 values)
__device__ __forceinline__ frag8 pack_bf16(f4 a, f4 b) {
  union { u32 w[4]; frag8 f; } u;
  asm("v_cvt_pk_bf16_f32 %0, %1, %2" : "=v"(u.w[0]) : "v"(a[0]), "v"(a[1]));
  asm("v_cvt_pk_bf16_f32 %0, %1, %2" : "=v"(u.w[1]) : "v"(a[2]), "v"(a[3]));
  asm("v_cvt_pk_bf16_f32 %0, %1, %2" : "=v"(u.w[2]) : "v"(b[0]), "v"(b[1]));
  asm("v_cvt_pk_bf16_f32 %0, %1, %2" : "=v"(u.w[3]) : "v"(b[2]), "v"(b[3]));
  return u.f;
}

// fp32 -> bf16 weight conversion (W_hh then W_ih), exact-sized grid.
__global__ void prep_bf16(const float* __restrict__ whh_f32,
                          const float* __restrict__ wih_f32,
                          u16* __restrict__ whh, u16* __restrict__ wih) {
  int i = blockIdx.x * 256 + threadIdx.x;
  const int nhh = 3072 * 1024;
  if (i < nhh) whh[i] = f2bf(whh_f32[i]);
  else         wih[i - nhh] = f2bf(wih_f32[i - nhh]);
}

// gi MFMAs, FIRST-WRITE form: C = zz (no ACC_ZERO needed for acc[.][0..3], accn)
#define IH_MFMA_F() do {                                                       \
  _Pragma("unroll") for (int rt_ = 0; rt_ < 4; ++rt_) {                        \
    acc[0][rt_] = __builtin_amdgcn_mfma_f32_16x16x32_bf16(smf0, wihf[rt_], zz, 0, 0, 0); \
    acc[1][rt_] = __builtin_amdgcn_mfma_f32_16x16x32_bf16(smf1, wihf[rt_], zz, 0, 0, 0); } \
  accn[0][0] = __builtin_amdgcn_mfma_f32_16x16x32_bf16(smf0, wihf[4], zz, 0, 0, 0); \
  accn[1][0] = __builtin_amdgcn_mfma_f32_16x16x32_bf16(smf1, wihf[4], zz, 0, 0, 0); \
  accn[0][1] = __builtin_amdgcn_mfma_f32_16x16x32_bf16(smf0, wihf[5], zz, 0, 0, 0); \
  accn[1][1] = __builtin_amdgcn_mfma_f32_16x16x32_bf16(smf1, wihf[5], zz, 0, 0, 0); \
} while (0)

// First hh chunk: kb=0 first-writes acc[.][4..5] (W_hh-only n slots) with C=zz.
#define HH_CHUNK0() do {                                                       \
  _Pragma("unroll") for (int rt_ = 0; rt_ < 4; ++rt_) {                        \
    acc[0][rt_] = __builtin_amdgcn_mfma_f32_16x16x32_bf16(af[0][0], whhf[0][rt_], acc[0][rt_], 0, 0, 0); \
    acc[1][rt_] = __builtin_amdgcn_mfma_f32_16x16x32_bf16(af[0][1], whhf[0][rt_], acc[1][rt_], 0, 0, 0); } \
  acc[0][4] = __builtin_amdgcn_mfma_f32_16x16x32_bf16(af[0][0], whhf[0][4], zz, 0, 0, 0); \
  acc[1][4] = __builtin_amdgcn_mfma_f32_16x16x32_bf16(af[0][1], whhf[0][4], zz, 0, 0, 0); \
  acc[0][5] = __builtin_amdgcn_mfma_f32_16x16x32_bf16(af[0][0], whhf[0][5], zz, 0, 0, 0); \
  acc[1][5] = __builtin_amdgcn_mfma_f32_16x16x32_bf16(af[0][1], whhf[0][5], zz, 0, 0, 0); \
  _Pragma("unroll") for (int rt_ = 0; rt_ < 6; ++rt_) {                        \
    acc[0][rt_] = __builtin_amdgcn_mfma_f32_16x16x32_bf16(af[1][0], whhf[1][rt_], acc[0][rt_], 0, 0, 0); \
    acc[1][rt_] = __builtin_amdgcn_mfma_f32_16x16x32_bf16(af[1][1], whhf[1][rt_], acc[1][rt_], 0, 0, 0); } \
} while (0)

// 12 hh MFMAs consuming af[2j], af[2j+1] (j >= 1).
#define HH_CHUNK(j) do {                                                       \
  _Pragma("unroll") for (int kk_ = 0; kk_ < 2; ++kk_) {                        \
    const int kb_ = 2 * (j) + kk_;                                             \
    _Pragma("unroll") for (int rt_ = 0; rt_ < 6; ++rt_) {                      \
      acc[0][rt_] = __builtin_amdgcn_mfma_f32_16x16x32_bf16(af[kb_][0], whhf[kb_][rt_], acc[0][rt_], 0, 0, 0); \
      acc[1][rt_] = __builtin_amdgcn_mfma_f32_16x16x32_bf16(af[kb_][1], whhf[kb_][rt_], acc[1][rt_], 0, 0, 0); } } \
} while (0)

// 4 dwordx4 coherent loads; issue order = vmcnt order. SC = cache bits:
// "sc0" (XCD-local, L2 coherence point) or "sc0 sc1" (device, LLC).
#define AF_LOAD(j, SC) asm volatile(                                           \
  "global_load_dwordx4 %0, %4, off " SC "\n\t"                                 \
  "global_load_dwordx4 %1, %4, off offset:1024 " SC "\n\t"                     \
  "global_load_dwordx4 %2, %4, off offset:2048 " SC "\n\t"                     \
  "global_load_dwordx4 %3, %4, off offset:3072 " SC                            \
  : "=&v"(af[2 * (j)][0]), "=&v"(af[2 * (j)][1]),                              \
    "=&v"(af[2 * (j) + 1][0]), "=&v"(af[2 * (j) + 1][1])                       \
  : "v"(pb + (j) * 4096))

#define H_STORE(SC) asm volatile("global_store_dwordx2 %0, %1, off " SC        \
  :: "v"(hwrite + off), "v"(pk) : "memory")

// Persistent GRU recurrence. 256 WGs = 8 groups (batch slices of 32) x 32 WGs
// (32 H-cols each). Group g = wg&7 co-resident on one XCD (runtime verified)
// -> h exchange (af loads, h stores) sc0 through the XCD L2 (R8 proven:
// FETCH_SIZE 2.63e6 -> 9.4e4 KB). Flags device scope (R9/R13: sub-device
// polls serve stale data). Barrier shape = R8 exactly (R2/R13/R14 showed it
// is locally optimal); this round shrinks serial VALU work inside the step:
// first-write MFMAs (no ACC_ZERO), cvt_pk_bf16 packing, separate sbuf region
// (drops one barrier).
__global__ __launch_bounds__(256, 1) void gru_kernel(
    const float* __restrict__ x,       // [256][1024][128]
    const float* __restrict__ b_ih,    // [3072]
    const float* __restrict__ b_hh,    // [3072]
    const u16* __restrict__ whh,       // [3072][1024] bf16
    const u16* __restrict__ wih,       // [3072][128] bf16
    u64* __restrict__ hbuf,            // [2][8][8192] u64 (64KB per (p,g))
    u32* __restrict__ flags,           // [8][32] monotonic step counters
    u32* __restrict__ xccarr,          // [256] xcc-id + 1
    float* __restrict__ st1)           // [256][2]
{
  __shared__ f4 xbuf[4096];            // 64 KB: [4 waves][128 gr][8 b-quads] swizzled
  __shared__ u16 sbuf2[32 * 40];       // 2.5 KB h-staging (separate -> no alias barrier)
  const int wg = blockIdx.x;
  const int g = wg & 7, w = wg >> 3;   // group spans one XCD under round-robin
  const int tid = threadIdx.x;
  const int v = tid >> 6;              // wave = K-slice of 256
  const int l = tid & 63;
  const int lm = l & 15, lq = l >> 4;

  // ---- load weight fragments into registers (persistent) ----
  frag8 whhf[8][6];
  frag8 wihf[6];
#pragma unroll
  for (int rt = 0; rt < 6; ++rt) {
    int grow = (rt >> 1) * 1024 + w * 32 + (rt & 1) * 16 + lm;  // global gate row
    wihf[rt] = *(const frag8*)(wih + grow * 128 + v * 32 + lq * 8);
#pragma unroll
    for (int kb = 0; kb < 8; ++kb)
      whhf[kb][rt] = *(const frag8*)(whh + grow * 1024 + v * 256 + kb * 32 + lq * 8);
  }

  // ---- update-phase constants ----
  const int uc = tid & 31;
  const int ub0 = (tid >> 5) << 2;
  const int colg = w * 32 + uc;
  const float bir = b_ih[colg],         bhr = b_hh[colg];
  const float biz = b_ih[1024 + colg],  bhz = b_hh[1024 + colg];
  const float bin_ = b_ih[2048 + colg], bhn = b_hh[2048 + colg];
  f4 hprev = {0.f, 0.f, 0.f, 0.f};

  const float* xb0 = x + (size_t)(g * 32 + lm) * 131072 + v * 32 + lq * 8;
  const float* xb1 = x + (size_t)(g * 32 + 16 + lm) * 131072 + v * 32 + lq * 8;

  u32* flagbase = flags + (g << 5);
  u32* fself = flagbase + w;
  const f4 zz = {0.f, 0.f, 0.f, 0.f};
  const float A1 = 1.0f - ALPHA;

  // ---- one-time XCD co-location check: barrier-style, no leader ----
  u32 myxcc;
  asm volatile("s_getreg_b32 %0, hwreg(HW_REG_XCC_ID)" : "=s"(myxcc));
  myxcc &= 15u;
  if (tid == 0) {
    u32 pub = myxcc + 1u;
    asm volatile("global_store_dword %0, %1, off sc0 sc1"
                 :: "v"(xccarr + wg), "v"(pub) : "memory");
  }
  if (tid < 64) {
    const u32* xp = xccarr + ((((tid & 31) << 3) | g));  // member (tid&31) of group g
    u32 vv;
    while (1) {
      asm volatile("global_load_dword %0, %1, off sc0 sc1\n\ts_waitcnt vmcnt(0)"
                   : "=v"(vv) : "v"(xp) : "memory");
      if (__ballot(vv != 0u) == ~0ull) break;
      __builtin_amdgcn_s_sleep(1);
    }
    u32 same = (__ballot(vv == myxcc + 1u) == ~0ull) ? 1u : 0u;
    if (tid == 0) *(volatile u32*)&xbuf[0] = same;
  }
  __syncthreads();
  const bool locl = (*(volatile u32*)&xbuf[0]) != 0u;
  __syncthreads();   // xbuf[0] consumed before first loop LDS write

  // ---- prologue: EMA(0) = x(0); pack; gi(0) MFMAs (first-write form) ----
  f4 e0a = *(const f4*)xb0, e0b = *(const f4*)(xb0 + 4);
  f4 e1a = *(const f4*)xb1, e1b = *(const f4*)(xb1 + 4);
  frag8 smf0 = pack_bf16(e0a, e0b), smf1 = pack_bf16(e1a, e1b);
  f4 acc[2][6], accn[2][2];
  IH_MFMA_F();

#pragma unroll 1
  for (int t = 0; t < 1024; ++t) {
    const char* hrd = (const char*)hbuf + ((size_t)((t & 1) * 8 + g) << 16);
    u64* hwrite = hbuf + (size_t)(((t + 1) & 1) * 8 + g) * 8192;

    // ---- issue h_t fragment loads (16x dwordx4; XCD L2 if local, LLC else) ----
    frag8 af[8][2];
    const char* pb = hrd + (v << 14) + (l << 4);
    if (locl) { AF_LOAD(0, "sc0"); AF_LOAD(1, "sc0"); AF_LOAD(2, "sc0"); AF_LOAD(3, "sc0"); }
    else      { AF_LOAD(0, "sc0 sc1"); AF_LOAD(1, "sc0 sc1"); AF_LOAD(2, "sc0 sc1"); AF_LOAD(3, "sc0 sc1"); }

    // ---- issue x(t+1) prefetch (plain cached loads; consumed post-sync) ----
    int tn = (t < 1023) ? t + 1 : 1023;  // clamp: last-iter loads are discarded
    const float* xp0 = xb0 + (size_t)tn * 128;
    const float* xp1 = xb1 + (size_t)tn * 128;
    f4 xa0n, xc0n, xa1n, xc1n;
    asm volatile(
      "global_load_dwordx4 %0, %4, off\n\t"
      "global_load_dwordx4 %1, %4, off offset:16\n\t"
      "global_load_dwordx4 %2, %5, off\n\t"
      "global_load_dwordx4 %3, %5, off offset:16"
      : "=&v"(xa0n), "=&v"(xc0n), "=&v"(xa1n), "=&v"(xc1n)
      : "v"(xp0), "v"(xp1));

    // ---- hh MFMAs in 4 chunks with counted vmcnt (20 outstanding:
    //      16 af + 4 x; chunk j needs af loads 0..4j+3 done) ----
    asm volatile("s_waitcnt vmcnt(16)"); __builtin_amdgcn_sched_barrier(0);
    HH_CHUNK0();
    asm volatile("s_waitcnt vmcnt(12)"); __builtin_amdgcn_sched_barrier(0);
    HH_CHUNK(1);
    asm volatile("s_waitcnt vmcnt(8)");  __builtin_amdgcn_sched_barrier(0);
    HH_CHUNK(2);
    asm volatile("s_waitcnt vmcnt(4)");  __builtin_amdgcn_sched_barrier(0);
    HH_CHUNK(3);

    // ---- write K-partials to LDS (transposed, XOR-swizzled, b128) ----
#pragma unroll
    for (int bh = 0; bh < 2; ++bh) {
      int b8 = bh * 4 + lq;
#pragma unroll
      for (int rt = 0; rt < 6; ++rt) {
        int gr = rt * 16 + lm;
        xbuf[((v * 128 + gr) << 3) | (b8 ^ (gr & 7))] = acc[bh][rt];
      }
#pragma unroll
      for (int nt = 0; nt < 2; ++nt) {
        int gr = 96 + nt * 16 + lm;
        xbuf[((v * 128 + gr) << 3) | (b8 ^ (gr & 7))] = accn[bh][nt];
      }
    }
    __syncthreads();   // (1) partials visible

    // ---- gate update: thread handles 4 batches (ub0..) x 1 col (uc) ----
    int swz = (ub0 >> 2) ^ (uc & 7);
    f4 sr = zz, sz4 = zz, gn4 = zz, gin4 = zz;
#pragma unroll
    for (int vv = 0; vv < 4; ++vv) {
      sr   += xbuf[((vv * 128 + uc) << 3) | swz];
      sz4  += xbuf[((vv * 128 + 32 + uc) << 3) | swz];
      gn4  += xbuf[((vv * 128 + 64 + uc) << 3) | swz];
      gin4 += xbuf[((vv * 128 + 96 + uc) << 3) | swz];
    }
    f4 h4;
#pragma unroll
    for (int i = 0; i < 4; ++i) {
      float rr = sigmf(sr[i] + bir + bhr);
      float zg = sigmf(sz4[i] + biz + bhz);
      float nn = tanhf_(gin4[i] + bin_ + rr * (gn4[i] + bhn));
      h4[i] = (1.0f - zg) * nn + zg * hprev[i];
    }
    hprev = h4;

    // ---- stage h(bf16) in separate sbuf (no alias barrier needed) ----
#pragma unroll
    for (int i = 0; i < 4; ++i) sbuf2[(ub0 + i) * 40 + uc] = f2bf(h4[i]);
    __syncthreads();   // (2) staging visible

    // ---- store h to hwrite: repack to 8B, A-fragment-ordered ----
    {
      int b = tid >> 3, c0 = (tid & 7) << 2;
      u64 pk = *(const u64*)(sbuf2 + b * 40 + c0);
      int off = ((w * 2 + (b >> 4)) * 64 + (b & 15) + 16 * (c0 >> 3)) * 2 + ((c0 & 7) >> 2);
      if (locl) H_STORE("sc0");
      else      H_STORE("sc0 sc1");
    }
    asm volatile("s_waitcnt vmcnt(0)" ::: "memory");  // h + x drained
    __syncthreads();   // (3) whole WG drained before signaling

    if (t < 1023) {
      // ---- arrive: fire-and-forget flag store (DEVICE scope, as proven) ----
      if (tid == 0)
        asm volatile("global_store_dword %0, %1, off sc0 sc1"
                     :: "v"(fself), "v"((u32)(t + 1)) : "memory");

      // x prefetch already retired; wave0 skips its in-flight flag store
      // (vmcnt retires in order: flag is the only outstanding op).
      if (tid < 64) asm volatile("s_waitcnt vmcnt(1)" ::: "memory");
      else          asm volatile("s_waitcnt vmcnt(0)" ::: "memory");
      __builtin_amdgcn_sched_barrier(0);

      // ---- overlapped with other WGs' arrival: EMA(t+1), pack, gi MFMAs ----
      e0a = A1 * xa0n + ALPHA * e0a; e0b = A1 * xc0n + ALPHA * e0b;
      e1a = A1 * xa1n + ALPHA * e1a; e1b = A1 * xc1n + ALPHA * e1b;
      if (t == 1022 && w == 0 && v == 0 && lq == 0) {
        // st_1 = EMA at t=1023; columns 1,2 for denorm
        st1[(g * 32 + lm) * 2 + 0] = e0a[1];
        st1[(g * 32 + lm) * 2 + 1] = e0a[2];
        st1[(g * 32 + 16 + lm) * 2 + 0] = e1a[1];
        st1[(g * 32 + 16 + lm) * 2 + 1] = e1a[2];
      }
      smf0 = pack_bf16(e0a, e0b); smf1 = pack_bf16(e1a, e1b);
      IH_MFMA_F();

      // ---- wait: 64-lane coalesced poll of all 32 group flags (DEVICE) ----
      if (tid < 64) {
        const u32* fp = flagbase + (tid & 31);
        u32 fv;
        while (1) {
          asm volatile("global_load_dword %0, %1, off sc0 sc1\n\t"
                       "s_waitcnt vmcnt(0)"
                       : "=v"(fv) : "v"(fp) : "memory");
          if (__ballot(fv > (u32)t) == ~0ull) break;
          __builtin_amdgcn_s_sleep(1);
        }
      }
      __syncthreads();   // (4) release whole WG into next step
    }
  }
}

// out[b][o] = (h_T[b] . W_fc[o] + b_fc[o] - a*st1[b][o]) / (1-a)
__global__ void fc_kernel(const u16* __restrict__ hbuf_bf,  // parity-0 region
                          const float* __restrict__ wfc,    // [2][1024]
                          const float* __restrict__ bfc,    // [2]
                          const float* __restrict__ st1,    // [256][2]
                          float* __restrict__ out)          // [256][2]
{
  int b = blockIdx.x, t = threadIdx.x;
  int g = b >> 5, bl = b & 31, bh = bl >> 4;
  int k0 = t * 4, kb = k0 >> 5, ko = k0 & 31;
  int lane = (bl & 15) + 16 * (ko >> 3);
  const u16* hp = hbuf_bf + (size_t)g * 32768 + ((kb * 2 + bh) * 64 + lane) * 8 + (ko & 7);
  float h0 = bf2f(hp[0]), h1 = bf2f(hp[1]), h2 = bf2f(hp[2]), h3 = bf2f(hp[3]);
  float s0 = h0 * wfc[k0] + h1 * wfc[k0 + 1] + h2 * wfc[k0 + 2] + h3 * wfc[k0 + 3];
  float s1 = h0 * wfc[1024 + k0] + h1 * wfc[1024 + k0 + 1] +
             h2 * wfc[1024 + k0 + 2] + h3 * wfc[1024 + k0 + 3];
#pragma unroll
  for (int off = 32; off > 0; off >>= 1) {
    s0 += __shfl_down(s0, off);
    s1 += __shfl_down(s1, off);
  }
  __shared__ float red[8];
  if ((t & 63) == 0) { red[(t >> 6) * 2] = s0; red[(t >> 6) * 2 + 1] = s1; }
  __syncthreads();
  if (t == 0) {
    float a0 = red[0] + red[2] + red[4] + red[6] + bfc[0];
    float a1 = red[1] + red[3] + red[5] + red[7] + bfc[1];
    float inv = 1.0f / (1.0f - ALPHA);
    out[b * 2 + 0] = (a0 - ALPHA * st1[b * 2 + 0]) * inv;
    out[b * 2 + 1] = (a1 - ALPHA * st1[b * 2 + 1]) * inv;
  }
}

extern "C" void kernel_launch(void* const* d_in, const int* in_sizes, int n_in,
                              void* d_out, int out_size, void* d_ws, size_t ws_size,
                              hipStream_t stream) {
  const float* x   = (const float*)d_in[0];
  const float* Wih = (const float*)d_in[1];
  const float* Whh = (const float*)d_in[2];
  const float* bih = (const float*)d_in[3];
  const float* bhh = (const float*)d_in[4];
  const float* Wfc = (const float*)d_in[5];
  const float* bfc = (const float*)d_in[6];
  char* ws = (char*)d_ws;
  u16* whh_bf = (u16*)(ws + WHH_OFF);
  u16* wih_bf = (u16*)(ws + WIH_OFF);
  u64* hbuf   = (u64*)(ws + HBUF_OFF);
  u32* flg    = (u32*)(ws + FLG_OFF);
  u32* xcc    = (u32*)(ws + XCC_OFF);
  float* st1  = (float*)(ws + ST1_OFF);

  hipMemsetAsync(ws + HBUF_OFF, 0, ZERO_LEN, stream);
  prep_bf16<<<13824, 256, 0, stream>>>(Whh, Wih, whh_bf, wih_bf);
  gru_kernel<<<256, 256, 0, stream>>>(x, bih, bhh, whh_bf, wih_bf, hbuf, flg, xcc, st1);
  fc_kernel<<<256, 256, 0, stream>>>((const u16*)(ws + HBUF_OFF), Wfc, bfc, st1,
                                     (float*)d_out);
}